// Round 4
// baseline (1311.410 us; speedup 1.0000x reference)
//
#include <hip/hip_runtime.h>
#include <cstddef>

// Problem constants (from reference)
#define NN 100000
#define NE 1600000
#define NH 5
#define NC 12
#define HC 60     // NH*NC
#define FN 128
#define FE 32
#define HID 16
#define NCLS 2

typedef float v4f __attribute__((ext_vector_type(4)));
typedef float f2v __attribute__((ext_vector_type(2)));
typedef _Float16 h2 __attribute__((ext_vector_type(2)));
typedef _Float16 h8 __attribute__((ext_vector_type(8)));

#if __has_builtin(__builtin_amdgcn_exp2f)
#define EXP2F(x) __builtin_amdgcn_exp2f(x)
#else
#define EXP2F(x) exp2f(x)
#endif

__device__ __forceinline__ float bperm(int idxb, float x) {
    return __int_as_float(__builtin_amdgcn_ds_bpermute(idxb, __float_as_int(x)));
}

// half2 dot with f32 accumulate: v_dot2_f32_f16 when available
__device__ __forceinline__ float dot2h(unsigned int u, h2 w, float c) {
    const h2 a = __builtin_bit_cast(h2, u);
#if __has_builtin(__builtin_amdgcn_fdot2)
    return __builtin_amdgcn_fdot2(a, w, c, false);
#else
    return fmaf((float)a[0], (float)w[0], fmaf((float)a[1], (float)w[1], c));
#endif
}

__device__ __forceinline__ f2v mk2(float a, float b) {
    f2v t; t[0] = a; t[1] = b; return t;
}
__device__ __forceinline__ f2v fma2(f2v a, float w, f2v c) {
#if __has_builtin(__builtin_elementwise_fma)
    f2v ww; ww[0] = w; ww[1] = w;
    return __builtin_elementwise_fma(a, ww, c);
#else
    f2v r; r[0] = fmaf(a[0], w, c[0]); r[1] = fmaf(a[1], w, c[1]); return r;
#endif
}

// ---------------------------------------------------------------------------
// qkvs: q,k,v,skip = X @ W? + b?  for 4 matrices [DIN,60].
// Wave w of each block owns matrix w (uniform W base per wave — no divergent
// pointer split). 16 nodes per block; lane = output column; node PAIRS packed
// into float2 accumulators (v_pk_fma_f32). X rows are wave-uniform ->
// s_load_dwordx4 on the SMEM pipe; no LDS, no barriers.
// k and v are written PACKED into kvb[node][120] (k: 0..59, v: 60..119).
// ---------------------------------------------------------------------------
template<int DIN>
__global__ __launch_bounds__(256) void qkvs_kernel(
    const float* __restrict__ X,
    const float* __restrict__ Wq, const float* __restrict__ bq,
    const float* __restrict__ Wk, const float* __restrict__ bk,
    const float* __restrict__ Wv, const float* __restrict__ bv,
    const float* __restrict__ Ws, const float* __restrict__ bs,
    float* __restrict__ qb, float* __restrict__ kvb, float* __restrict__ sb)
{
    constexpr int NB = 16;
    const int n0 = blockIdx.x * NB;            // NN == 16*6250 exactly
    const int w = threadIdx.x >> 6, lane = threadIdx.x & 63;
    const int cl = (lane < 60) ? lane : 0;     // clamp: avoid OOB W reads
    const float* W; const float* b; float* outp; int ostr;
    switch (w) {
        case 0:  W = Wq; b = bq; outp = qb;       ostr = 60;  break;
        case 1:  W = Wk; b = bk; outp = kvb;      ostr = 120; break;
        case 2:  W = Wv; b = bv; outp = kvb + 60; ostr = 120; break;
        default: W = Ws; b = bs; outp = sb;       ostr = 60;  break;
    }
    const float* __restrict__ xr = X + (size_t)n0 * DIN;   // wave-uniform
    f2v acc[8] = {};
    for (int r = 0; r < DIN; r += 4) {
        const float w0 = W[(r + 0) * 60 + cl];
        const float w1 = W[(r + 1) * 60 + cl];
        const float w2 = W[(r + 2) * 60 + cl];
        const float w3 = W[(r + 3) * 60 + cl];
        #pragma unroll
        for (int p = 0; p < 8; ++p) {
            const float4 xa = *(const float4*)(xr + (size_t)(2 * p)     * DIN + r);
            const float4 xb = *(const float4*)(xr + (size_t)(2 * p + 1) * DIN + r);
            acc[p] = fma2(mk2(xa.x, xb.x), w0, acc[p]);
            acc[p] = fma2(mk2(xa.y, xb.y), w1, acc[p]);
            acc[p] = fma2(mk2(xa.z, xb.z), w2, acc[p]);
            acc[p] = fma2(mk2(xa.w, xb.w), w3, acc[p]);
        }
    }
    if (lane < 60) {
        const float bb = b[lane];
        #pragma unroll
        for (int p = 0; p < 8; ++p) {
            outp[(size_t)(n0 + 2 * p)     * ostr + lane] = acc[p][0] + bb;
            outp[(size_t)(n0 + 2 * p + 1) * ostr + lane] = acc[p][1] + bb;
        }
    }
}

// ---------------------------------------------------------------------------
// CSR build: histogram of dst -> exclusive scan -> scatter edge ids (+src ids)
// ---------------------------------------------------------------------------
__global__ __launch_bounds__(256) void hist_kernel(
    const int* __restrict__ ei, int* __restrict__ cnt)
{
    const int e = blockIdx.x * 256 + threadIdx.x;
    if (e < NE) atomicAdd(&cnt[ei[NE + e]], 1);
}

__global__ __launch_bounds__(1024) void scan1_kernel(
    const int* __restrict__ cnt, int* __restrict__ excl, int* __restrict__ bsum)
{
    __shared__ int sh[1024];
    const int i = blockIdx.x * 1024 + threadIdx.x;
    const int v = (i < NN) ? cnt[i] : 0;
    sh[threadIdx.x] = v;
    __syncthreads();
    for (int off = 1; off < 1024; off <<= 1) {
        const int t = (threadIdx.x >= off) ? sh[threadIdx.x - off] : 0;
        __syncthreads();
        sh[threadIdx.x] += t;
        __syncthreads();
    }
    if (i < NN) excl[i] = sh[threadIdx.x] - v;     // block-local exclusive
    if (threadIdx.x == 1023) bsum[blockIdx.x] = sh[1023];
}

// parallel block-sum scan (128 threads >= 98 blocks)
__global__ __launch_bounds__(128) void scan2_kernel(
    int* __restrict__ bsum, int nb, int* __restrict__ start)
{
    __shared__ int sh[128];
    const int i = threadIdx.x;
    const int v = (i < nb) ? bsum[i] : 0;
    sh[i] = v;
    __syncthreads();
    for (int off = 1; off < 128; off <<= 1) {
        const int tv = (i >= off) ? sh[i - off] : 0;
        __syncthreads();
        sh[i] += tv;
        __syncthreads();
    }
    if (i < nb) bsum[i] = sh[i] - v;      // exclusive
    if (i == 127) start[NN] = sh[127];    // total == NE
}

// fused: finalize start[] AND write cursor[] (kills the D2D memcpy dispatch)
__global__ __launch_bounds__(1024) void scan3_kernel(
    int* __restrict__ start, const int* __restrict__ bsum,
    int* __restrict__ cursor)
{
    const int i = blockIdx.x * 1024 + threadIdx.x;
    if (i < NN) {
        const int v = start[i] + bsum[blockIdx.x];
        start[i] = v;
        cursor[i] = v;
    }
}

// scatter: perm + srcs only (4B scattered writes — cheap; r2 showed fused
// 128B row writes cause 4x write amplification).
__global__ __launch_bounds__(256) void scatter_kernel(
    const int* __restrict__ ei, int* __restrict__ cursor,
    int* __restrict__ perm, int* __restrict__ srcs)
{
    const int e = blockIdx.x * 256 + threadIdx.x;
    if (e >= NE) return;
    const int d = ei[NE + e];
    const int pos = atomicAdd(&cursor[d], 1);
    perm[pos] = e;
    srcs[pos] = ei[e];
}

// ---------------------------------------------------------------------------
// permea: eaPh[slot] = fp16(ea[perm[slot]])  (CSR order, half precision).
// Gather-read row-coalesced; write position-linear 16B/thread.
// ---------------------------------------------------------------------------
__global__ __launch_bounds__(256) void permea_kernel(
    const int* __restrict__ perm, const float* __restrict__ ea,
    h8* __restrict__ eaPh)
{
    const int t = blockIdx.x * 256 + threadIdx.x;   // NE*4 threads
    const int slot = t >> 2, part = t & 3;
    const int e = perm[slot];
    const float4* src = (const float4*)(ea + (size_t)e * FE) + 2 * part;
    const float4 a = src[0];
    const float4 b = src[1];
    h8 o;
    o[0] = (_Float16)a.x; o[1] = (_Float16)a.y;
    o[2] = (_Float16)a.z; o[3] = (_Float16)a.w;
    o[4] = (_Float16)b.x; o[5] = (_Float16)b.y;
    o[6] = (_Float16)b.z; o[7] = (_Float16)b.w;
    eaPh[(size_t)slot * 4 + part] = o;
}

// ---------------------------------------------------------------------------
// Aggregation: TWO nodes per wave (n, n+NN/2), lane = channel hc for both.
// Rationale (r3 post-mortem): latency-bound, not BW-bound — doubling the
// independent per-wave pipelines doubles misses in flight and fills each
// stall window with the other node's VALU/LDS work. All predication is
// wave-uniform (scalar edge counts) -> no divergence.
// - eaPh rows + srcs at uniform addresses -> s_load pipeline
// - packed kv rows: k at +0, v at +60 (one contiguous 480B gather per edge)
// - per-head reduce: depth-2, 5 ds_bpermute with precomputed byte indices
// ---------------------------------------------------------------------------
template<bool LIN>
__global__ __launch_bounds__(256) void agg_kernel(
    const int* __restrict__ perm, const int* __restrict__ srcs,
    const int* __restrict__ start,
    const _Float16* __restrict__ eaH, const float* __restrict__ eaF,
    const float* __restrict__ We,
    const float* __restrict__ q, const float* __restrict__ kv,
    const float* __restrict__ sk, float* __restrict__ hout)
{
    const int wv   = threadIdx.x >> 6;
    const int lane = threadIdx.x & 63;
    const int hc   = (lane < 60) ? lane : 0;
    const int hd    = hc / NC;
    const int hbase = hd * NC;
    const int c     = hc - hbase;

    const int i1 = (hbase + (c + 3) % 12) << 2;
    const int i2 = (hbase + (c + 6) % 12) << 2;
    const int i3 = (hbase + (c + 9) % 12) << 2;
    const int j1 = (hbase + (c + 1) % 3) << 2;
    const int j2 = (hbase + (c + 2) % 3) << 2;

    auto tail = [&](float eacc, float KV, float VV, float qv,
                    float& A, float& D) {
        const float p = qv * (KV + eacc);
        const float f = (p + bperm(i1, p)) + (bperm(i2, p) + bperm(i3, p));
        const float a = (f + bperm(j1, f)) + bperm(j2, f);
        // exp(a/sqrt(12) - 20) == exp2(a * log2e/sqrt(12) - 20*log2e)
        const float w = EXP2F(fmaf(a, 0.41647013f, -28.8539009f));
        A = fmaf(w, VV + eacc, A);
        D += w;
    };

    if constexpr (LIN) {
        const int g  = blockIdx.x * 4 + wv;     // 0 .. NN/2-1
        const int n1 = g, n2 = g + NN / 2;

        h2 WH[16];                              // fp16 We column, 16 half2
        #pragma unroll
        for (int p = 0; p < 16; ++p) {
            h2 wvv;
            wvv[0] = (_Float16)We[(2 * p)     * 60 + hc];
            wvv[1] = (_Float16)We[(2 * p + 1) * 60 + hc];
            WH[p] = wvv;
        }

        const float qv1 = q[(size_t)n1 * 60 + hc];
        const float sv1 = sk[(size_t)n1 * 60 + hc];
        const float qv2 = q[(size_t)n2 * 60 + hc];
        const float sv2 = sk[(size_t)n2 * 60 + hc];

        const int a0 = __builtin_amdgcn_readfirstlane(start[n1]);
        const int a1 = __builtin_amdgcn_readfirstlane(start[n1 + 1]);
        const int b0 = __builtin_amdgcn_readfirstlane(start[n2]);
        const int b1 = __builtin_amdgcn_readfirstlane(start[n2 + 1]);
        const int c1 = a1 - a0, c2 = b1 - b0;
        const int mx = (c1 > c2) ? c1 : c2;

        float acc1 = 0.f, den1 = 0.f, acc2 = 0.f, den2 = 0.f;

        auto drow = [&](const uint4 (&E)[4]) -> float {
            float d0 = 0.f, d1 = 0.f;
            #pragma unroll
            for (int i = 0; i < 4; ++i) {
                d0 = dot2h(E[i].x, WH[4 * i + 0], d0);
                d1 = dot2h(E[i].y, WH[4 * i + 1], d1);
                d0 = dot2h(E[i].z, WH[4 * i + 2], d0);
                d1 = dot2h(E[i].w, WH[4 * i + 3], d1);
            }
            return d0 + d1;
        };
        auto ldea = [&](uint4 (&E)[4], int t) {
            const uint4* er = (const uint4*)(eaH + (size_t)t * FE);  // 64B row
            E[0] = er[0]; E[1] = er[1]; E[2] = er[2]; E[3] = er[3];
        };
        auto ldkv = [&](float& K, float& V, int t) {
            const float* r = kv + (size_t)srcs[t] * 120;   // srcs[t] -> s_load
            K = r[hc]; V = r[60 + hc];
        };

        uint4 eA1[4], eB1[4], eA2[4], eB2[4];
        float kA1 = 0.f, vA1 = 0.f, kB1 = 0.f, vB1 = 0.f;
        float kA2 = 0.f, vA2 = 0.f, kB2 = 0.f, vB2 = 0.f;

        if (c1 > 0) { ldkv(kA1, vA1, a0);     ldea(eA1, a0);     }
        if (c1 > 1) { ldkv(kB1, vB1, a0 + 1); ldea(eB1, a0 + 1); }
        if (c2 > 0) { ldkv(kA2, vA2, b0);     ldea(eA2, b0);     }
        if (c2 > 1) { ldkv(kB2, vB2, b0 + 1); ldea(eB2, b0 + 1); }

        for (int i = 0; i < mx; i += 2) {
            if (i < c1)     tail(drow(eA1), kA1, vA1, qv1, acc1, den1);
            if (i < c2)     tail(drow(eA2), kA2, vA2, qv2, acc2, den2);
            if (i + 2 < c1) { ldkv(kA1, vA1, a0 + i + 2); ldea(eA1, a0 + i + 2); }
            if (i + 2 < c2) { ldkv(kA2, vA2, b0 + i + 2); ldea(eA2, b0 + i + 2); }
            if (i + 1 < c1) tail(drow(eB1), kB1, vB1, qv1, acc1, den1);
            if (i + 1 < c2) tail(drow(eB2), kB2, vB2, qv2, acc2, den2);
            if (i + 3 < c1) { ldkv(kB1, vB1, a0 + i + 3); ldea(eB1, a0 + i + 3); }
            if (i + 3 < c2) { ldkv(kB2, vB2, b0 + i + 3); ldea(eB2, b0 + i + 3); }
        }

        if (lane < 60) {
            hout[(size_t)n1 * 60 + hc] = fmaxf(acc1 / (den1 + 1e-16f) + sv1, 0.f);
            hout[(size_t)n2 * 60 + hc] = fmaxf(acc2 / (den2 + 1e-16f) + sv2, 0.f);
        }
    } else {
        // fallback (workspace too small): f32, perm-indexed, two nodes serial
        float Wcol[FE];
        #pragma unroll
        for (int r = 0; r < FE; ++r) Wcol[r] = We[r * 60 + hc];
        const int g = blockIdx.x * 4 + wv;
        #pragma unroll 1
        for (int pass = 0; pass < 2; ++pass) {
            const int n = pass ? (g + NN / 2) : g;
            const float qv = q[(size_t)n * 60 + hc];
            const float sv = sk[(size_t)n * 60 + hc];
            const int s0 = __builtin_amdgcn_readfirstlane(start[n]);
            const int s1 = __builtin_amdgcn_readfirstlane(start[n + 1]);
            float acc = 0.f, den = 0.f;
            for (int t = s0; t < s1; ++t) {
                const int e = perm[t];
                const float* __restrict__ er = eaF + (size_t)e * FE;
                float e0 = 0.f, e1 = 0.f;
                #pragma unroll
                for (int r = 0; r < FE; r += 2) {
                    e0 = fmaf(er[r],     Wcol[r],     e0);
                    e1 = fmaf(er[r + 1], Wcol[r + 1], e1);
                }
                const float* kr = kv + (size_t)srcs[t] * 120;
                tail(e0 + e1, kr[hc], kr[60 + hc], qv, acc, den);
            }
            if (lane < 60)
                hout[(size_t)n * 60 + hc] = fmaxf(acc / (den + 1e-16f) + sv, 0.f);
        }
    }
}

// ---------------------------------------------------------------------------
// MLP head: out = relu(h @ W1 + b1) @ W2 + b2     (one thread per node)
// ---------------------------------------------------------------------------
__global__ __launch_bounds__(256) void mlp_kernel(
    const float* __restrict__ h,
    const float* __restrict__ W1, const float* __restrict__ b1,
    const float* __restrict__ W2, const float* __restrict__ b2,
    float* __restrict__ out)
{
    __shared__ float sW1[60 * HID];
    __shared__ float sb1[HID];
    __shared__ float sW2[HID * NCLS];
    __shared__ float sb2[NCLS];
    for (int i = threadIdx.x; i < 60 * HID; i += 256) sW1[i] = W1[i];
    if (threadIdx.x < HID)        sb1[threadIdx.x] = b1[threadIdx.x];
    if (threadIdx.x < HID * NCLS) sW2[threadIdx.x] = W2[threadIdx.x];
    if (threadIdx.x < NCLS)       sb2[threadIdx.x] = b2[threadIdx.x];
    __syncthreads();

    const int n = blockIdx.x * 256 + threadIdx.x;
    if (n >= NN) return;
    const float* __restrict__ hr = h + (size_t)n * 60;
    float hv[60];
    #pragma unroll
    for (int i = 0; i < 15; ++i) {
        const float4 t = ((const float4*)hr)[i];
        hv[4 * i + 0] = t.x; hv[4 * i + 1] = t.y;
        hv[4 * i + 2] = t.z; hv[4 * i + 3] = t.w;
    }
    float o0 = sb2[0], o1 = sb2[1];
    for (int j = 0; j < HID; ++j) {
        float t = sb1[j];
        #pragma unroll
        for (int i = 0; i < 60; ++i) t = fmaf(hv[i], sW1[i * HID + j], t);
        t = fmaxf(t, 0.f);
        o0 = fmaf(t, sW2[2 * j + 0], o0);
        o1 = fmaf(t, sW2[2 * j + 1], o1);
    }
    out[(size_t)n * 2 + 0] = o0;
    out[(size_t)n * 2 + 1] = o1;
}

// ---------------------------------------------------------------------------
extern "C" void kernel_launch(void* const* d_in, const int* in_sizes, int n_in,
                              void* d_out, int out_size, void* d_ws, size_t ws_size,
                              hipStream_t stream)
{
    const float* x   = (const float*)d_in[0];
    const int*   ei  = (const int*)  d_in[1];
    const float* ea  = (const float*)d_in[2];
    const float* Wq1 = (const float*)d_in[3];  const float* bq1 = (const float*)d_in[4];
    const float* Wk1 = (const float*)d_in[5];  const float* bk1 = (const float*)d_in[6];
    const float* Wv1 = (const float*)d_in[7];  const float* bv1 = (const float*)d_in[8];
    const float* We1 = (const float*)d_in[9];
    const float* Ws1 = (const float*)d_in[10]; const float* bs1 = (const float*)d_in[11];
    const float* Wq2 = (const float*)d_in[12]; const float* bq2 = (const float*)d_in[13];
    const float* Wk2 = (const float*)d_in[14]; const float* bk2 = (const float*)d_in[15];
    const float* Wv2 = (const float*)d_in[16]; const float* bv2 = (const float*)d_in[17];
    const float* We2 = (const float*)d_in[18];
    const float* Ws2 = (const float*)d_in[19]; const float* bs2 = (const float*)d_in[20];
    const float* W1  = (const float*)d_in[21]; const float* b1  = (const float*)d_in[22];
    const float* W2  = (const float*)d_in[23]; const float* b2  = (const float*)d_in[24];
    float* out = (float*)d_out;

    // workspace: [ints][pad->256B][qb | kvb(2x) | sb | h0][eaPh NE*32 halves]
    int* cnt    = (int*)d_ws;             // NN
    int* startp = cnt + NN;               // NN+1
    int* cursor = startp + NN + 1;        // NN
    int* bsum   = cursor + NN;            // 128
    int* perm   = bsum + 128;             // NE
    int* srcs   = perm + NE;              // NE
    const size_t int_bytes = (size_t)(3 * NN + 1 + 128 + 2 * NE) * sizeof(int);
    const size_t f_off = (int_bytes + 255) & ~(size_t)255;
    const size_t NHC = (size_t)NN * 60;
    float* qb  = (float*)((char*)d_ws + f_off);
    float* kvb = qb + NHC;                // NN*120 packed k|v
    float* sb  = kvb + 2 * NHC;
    float* h0  = sb + NHC;                // layer1 out; overwritten by layer2 out
    _Float16* eaPh = (_Float16*)(h0 + NHC);   // NE*32 halves (CSR-ordered)
    const size_t need = f_off + 5 * NHC * sizeof(float)
                      + (size_t)NE * FE * sizeof(_Float16);
    const bool lin = ws_size >= need;

    const int qkvs_blocks = NN / 16;               // 6250 exact
    const int e256_blocks = NE / 256;              // 6250 exact
    const int scan_blocks = (NN + 1023) / 1024;    // 98
    const int agg_blocks  = NN / 8;                // 12500 exact (2 nodes/wave)
    const int mlp_blocks  = (NN + 255) / 256;      // 391
    const int perm_blocks = NE * 4 / 256;          // 25000 exact

    // ---- CSR build (once, shared by both layers) ----
    hipMemsetAsync(cnt, 0, (size_t)NN * sizeof(int), stream);
    hist_kernel<<<e256_blocks, 256, 0, stream>>>(ei, cnt);
    scan1_kernel<<<scan_blocks, 1024, 0, stream>>>(cnt, startp, bsum);
    scan2_kernel<<<1, 128, 0, stream>>>(bsum, scan_blocks, startp);
    scan3_kernel<<<scan_blocks, 1024, 0, stream>>>(startp, bsum, cursor);
    scatter_kernel<<<e256_blocks, 256, 0, stream>>>(ei, cursor, perm, srcs);
    if (lin)
        permea_kernel<<<perm_blocks, 256, 0, stream>>>(perm, ea, (h8*)eaPh);

    // ---- layer 1 ----
    qkvs_kernel<FN><<<qkvs_blocks, 256, 0, stream>>>(
        x, Wq1, bq1, Wk1, bk1, Wv1, bv1, Ws1, bs1, qb, kvb, sb);
    if (lin)
        agg_kernel<true><<<agg_blocks, 256, 0, stream>>>(
            perm, srcs, startp, eaPh, ea, We1, qb, kvb, sb, h0);
    else
        agg_kernel<false><<<agg_blocks, 256, 0, stream>>>(
            perm, srcs, startp, eaPh, ea, We1, qb, kvb, sb, h0);

    // ---- layer 2 ----
    qkvs_kernel<HC><<<qkvs_blocks, 256, 0, stream>>>(
        h0, Wq2, bq2, Wk2, bk2, Wv2, bv2, Ws2, bs2, qb, kvb, sb);
    if (lin)
        agg_kernel<true><<<agg_blocks, 256, 0, stream>>>(
            perm, srcs, startp, eaPh, ea, We2, qb, kvb, sb, h0);
    else
        agg_kernel<false><<<agg_blocks, 256, 0, stream>>>(
            perm, srcs, startp, eaPh, ea, We2, qb, kvb, sb, h0);   // h0 reuse safe

    // ---- MLP head ----
    mlp_kernel<<<mlp_blocks, 256, 0, stream>>>(h0, W1, b1, W2, b2, out);
}